// Round 8
// baseline (312.497 us; speedup 1.0000x reference)
//
#include <hip/hip_runtime.h>

// ---------------------------------------------------------------------------
// GNN: 2x SAGEConv(mean) + ReLU, global mean pool, 2-layer MLP classifier.
// N=50000 nodes, E=600000 edges, F=H=128, 64 graphs. fp32 in/out.
// R2: hierarchical scan. R3: pool fused into linear epilogue.
// R4: gcnt via binary search. R5: linear -> MFMA bf16x3. R6: bf16 gather.
// R7: CSR via two-level counting sort (LDS atomics only).
// R8: (a) k_bscan was 147 serial dependent global RMWs/thread (~25us) ->
//         split into parallel bscan_a/bscan_b.
//     (b) agg fused into MFMA linear (k_fused): agg tile built in LDS,
//         T (51MB/layer) never hits HBM; gather overlaps MFMA across blocks.
//     (c) h1 kept bf16-only (X-term lo=0, al-MFMA skipped in layer 2).
// ---------------------------------------------------------------------------

typedef __attribute__((ext_vector_type(8))) short bf16x8;
typedef __attribute__((ext_vector_type(8))) unsigned short ushort8;
typedef __attribute__((ext_vector_type(4))) float f32x4;

#define HBLK 4096  // edges per block in the bucket passes

__device__ inline unsigned short f2bf(float f) {
  unsigned u = __float_as_uint(f);
  u += 0x7fff + ((u >> 16) & 1);  // round-to-nearest-even
  return (unsigned short)(u >> 16);
}
__device__ inline float bf2f(unsigned short h) { return __uint_as_float(((unsigned)h) << 16); }

// ---- CSR build: two-level counting sort (no global atomics) ---------------
// Bucket key = dst>>8 (256 buckets covers N<=65536).

__global__ __launch_bounds__(256) void k_hist(const int* __restrict__ ei, int* __restrict__ bhist, int E) {
  __shared__ int h[256];
  int tid = threadIdx.x;
  h[tid] = 0;
  __syncthreads();
  int base = blockIdx.x * HBLK;
  int end = min(base + HBLK, E);
  for (int e = base + tid; e < end; e += 256) {
    int d = ei[E + e];
    atomicAdd(&h[d >> 8], 1);
  }
  __syncthreads();
  bhist[blockIdx.x * 256 + tid] = h[tid];
}

// bucket totals + exclusive scan -> bukbase[257]
__global__ __launch_bounds__(256) void k_bscan_a(const int* __restrict__ bhist, int* __restrict__ bukbase,
                                                 int nblk) {
  __shared__ int s[256];
  int t = threadIdx.x;
  int sum = 0;
  for (int b = 0; b < nblk; ++b) sum += bhist[b * 256 + t];  // coalesced, independent loads
  s[t] = sum;
  __syncthreads();
  for (int d = 1; d < 256; d <<= 1) {
    int v = (t >= d) ? s[t - d] : 0;
    __syncthreads();
    s[t] += v;
    __syncthreads();
  }
  bukbase[t] = s[t] - sum;  // exclusive
  if (t == 255) bukbase[256] = s[255];
}

// per-bucket scan over blocks: bhist[b][buk] = bukbase[buk] + prefix_{b'<b}
__global__ __launch_bounds__(256) void k_bscan_b(int* __restrict__ bhist, const int* __restrict__ bukbase,
                                                 int nblk) {
  __shared__ int s[256];
  int buk = blockIdx.x;
  int t = threadIdx.x;
  int c = (t < nblk) ? bhist[t * 256 + buk] : 0;
  s[t] = c;
  __syncthreads();
  for (int d = 1; d < 256; d <<= 1) {
    int v = (t >= d) ? s[t - d] : 0;
    __syncthreads();
    s[t] += v;
    __syncthreads();
  }
  if (t < nblk) bhist[t * 256 + buk] = bukbase[buk] + s[t] - c;
}

// scatter edges into bucket order, packed (dstLow8<<24 | src)
__global__ __launch_bounds__(256) void k_scat(const int* __restrict__ ei, const int* __restrict__ bhist,
                                              unsigned* __restrict__ ebuk, int E) {
  __shared__ int cur[256];
  int tid = threadIdx.x;
  cur[tid] = bhist[blockIdx.x * 256 + tid];
  __syncthreads();
  int base = blockIdx.x * HBLK;
  int end = min(base + HBLK, E);
  for (int e = base + tid; e < end; e += 256) {
    int d = ei[E + e];
    int srcv = ei[e];
    int p = atomicAdd(&cur[d >> 8], 1);
    ebuk[p] = ((unsigned)(d & 255) << 24) | (unsigned)srcv;
  }
}

// per-bucket local counting sort -> off (coalesced) + col
__global__ __launch_bounds__(256) void k_bucket(const unsigned* __restrict__ ebuk,
                                                const int* __restrict__ bukbase,
                                                int* __restrict__ off, int* __restrict__ colv,
                                                int N, int E) {
  __shared__ int h[256];
  __shared__ int cur[256];
  __shared__ int sc[256];
  int tid = threadIdx.x;
  int buk = blockIdx.x;
  int b0 = bukbase[buk], b1 = bukbase[buk + 1];
  h[tid] = 0;
  __syncthreads();
  for (int i = b0 + tid; i < b1; i += 256) atomicAdd(&h[ebuk[i] >> 24], 1);
  __syncthreads();
  int my = h[tid];
  sc[tid] = my;
  __syncthreads();
  for (int d = 1; d < 256; d <<= 1) {
    int v = (tid >= d) ? sc[tid - d] : 0;
    __syncthreads();
    sc[tid] += v;
    __syncthreads();
  }
  int excl = sc[tid] - my;
  cur[tid] = excl;
  int node = buk * 256 + tid;
  if (node < N) off[node] = b0 + excl;
  if (buk == gridDim.x - 1 && tid == 0) off[N] = E;
  __syncthreads();
  for (int i = b0 + tid; i < b1; i += 256) {
    unsigned v = ebuk[i];
    int p = atomicAdd(&cur[v >> 24], 1);
    colv[b0 + p] = (int)(v & 0xFFFFFFu);
  }
}

// ---- gcnt via binary search on sorted batch -------------------------------

__global__ __launch_bounds__(64) void k_gcnt_bs(const int* __restrict__ batch, int* __restrict__ gcnt,
                                                int N, int G) {
  int g = threadIdx.x;
  if (g >= G) return;
  int lo = 0, hi = N;
  while (lo < hi) { int mid = (lo + hi) >> 1; if (batch[mid] < g) lo = mid + 1; else hi = mid; }
  int a = lo;
  lo = 0; hi = N;
  while (lo < hi) { int mid = (lo + hi) >> 1; if (batch[mid] < g + 1) lo = mid + 1; else hi = mid; }
  gcnt[g] = lo - a;
}

// ---- fp32 -> bf16 convert (gather source) ---------------------------------

__global__ __launch_bounds__(256) void k_tobf(const float* __restrict__ x,
                                              unsigned short* __restrict__ xbf, int total) {
  int i = (blockIdx.x * 256 + threadIdx.x) * 4;
  if (i + 3 < total) {
    float4 v = *(const float4*)(x + i);
    ushort4 p;
    p.x = f2bf(v.x); p.y = f2bf(v.y); p.z = f2bf(v.z); p.w = f2bf(v.w);
    *(ushort4*)(xbf + i) = p;
  } else {
    for (int k = 0; k < 4 && i + k < total; ++k) xbf[i + k] = f2bf(x[i + k]);
  }
}

// ---- weight prep: split fp32 W into bf16 hi/lo, fragment-linear -----------
// Bpre layout: [kk 8][half 2][ct 8][lane 64][j 8] bf16 (65536 shorts = 128KB)

__global__ __launch_bounds__(256) void k_wprep(const float* __restrict__ Wl, const float* __restrict__ Wr,
                                               unsigned short* __restrict__ Bpre) {
  int id = blockIdx.x * 256 + threadIdx.x;  // 4096 slots
  if (id >= 4096) return;
  int kk = id >> 9;
  int ct = (id >> 6) & 7;
  int l  = id & 63;
  int colIdx = ct * 16 + (l & 15);
  int k0 = kk * 32 + (l >> 4) * 8;
  const float* W = (k0 < 128) ? Wl : Wr;
  int kb = k0 & 127;
#pragma unroll
  for (int j = 0; j < 8; ++j) {
    float v = W[colIdx * 128 + kb + j];
    unsigned short h = f2bf(v);
    size_t bh = (size_t)kk * 8192 + ((size_t)ct * 64 + l) * 8 + j;
    Bpre[bh] = h;
    Bpre[bh + 4096] = f2bf(v - bf2f(h));
  }
}

// ---- fused SAGE layer: H = relu(mean_nbr(G) @ Wl.T + X @ Wr.T + b) --------
// Phase 1: aggregate 64 nodes into LDS A-tile (bf16 hi/lo, fp32-accurate).
// Phase 2: MFMA K-loop (K=256: kk 0..3 = agg term from LDS, 4..7 = self term).
// mode 0 (layer 1): X = Xf (fp32), write OUTbf (h1 bf16).
// mode 1 (layer 2): X = Xbf (bf16, lo=0, al-MFMA skipped), pool into gsum.

__global__ __launch_bounds__(256) void k_fused(
    const unsigned short* __restrict__ Gsrc,  // gather source [N][128] bf16
    const float* __restrict__ Xf,             // self source fp32 (mode 0)
    const unsigned short* __restrict__ Xbf,   // self source bf16 (mode 1)
    const int* __restrict__ off, const int* __restrict__ col,
    const unsigned short* __restrict__ Bpre,
    const float* __restrict__ bias,
    unsigned short* __restrict__ OUTbf,
    const int* __restrict__ batch, float* __restrict__ gsum,
    int N, int mode) {
  __shared__ unsigned short AsF[16384];  // [half 2][kk 4][slot 256][8]  32KB
  __shared__ unsigned short Bs[8192];    // [half 2][ct 8][lane 64][8]   16KB
  __shared__ unsigned short Xs[4096];    // [half 2][slot 256][8]         8KB
  __shared__ float ps[128];

  int tid = threadIdx.x;
  int wv = tid >> 6, ln = tid & 63;
  int rowBase = blockIdx.x * 64;
  int rs = ln >> 4, fs = ln & 15;

  // ---------------- phase 1: aggregate 16 nodes per wave ----------------
  for (int n = 0; n < 16; ++n) {
    int row = wv * 16 + n;
    int node = rowBase + row;
    float acc[8];
#pragma unroll
    for (int j = 0; j < 8; ++j) acc[j] = 0.f;
    if (node < N) {  // wave-uniform branch
      int o0 = off[node], o1 = off[node + 1];
      int deg = o1 - o0;
      for (int base = 0; base < deg; base += 16) {
#pragma unroll
        for (int u = 0; u < 4; ++u) {
          int r = base + u * 4 + rs;
          if (r < deg) {
            int idx = col[o0 + r];
            ushort8 q = *(const ushort8*)(Gsrc + (size_t)idx * 128 + fs * 8);
#pragma unroll
            for (int j = 0; j < 8; ++j) acc[j] += bf2f(q[j]);
          }
        }
      }
      float sc = 1.0f / (float)max(deg, 1);
#pragma unroll
      for (int j = 0; j < 8; ++j) {
        acc[j] += __shfl_xor(acc[j], 16);
        acc[j] += __shfl_xor(acc[j], 32);
        acc[j] *= sc;
      }
    }
    if (rs < 2) {  // rs=0 writes hi, rs=1 writes lo
      unsigned short w[8];
#pragma unroll
      for (int j = 0; j < 8; ++j) {
        unsigned short h = f2bf(acc[j]);
        w[j] = (rs == 0) ? h : f2bf(acc[j] - bf2f(h));
      }
      uint4 uw;
      uw.x = (unsigned)w[0] | ((unsigned)w[1] << 16);
      uw.y = (unsigned)w[2] | ((unsigned)w[3] << 16);
      uw.z = (unsigned)w[4] | ((unsigned)w[5] << 16);
      uw.w = (unsigned)w[6] | ((unsigned)w[7] << 16);
      int slot = (row >> 4) * 64 + (fs & 3) * 16 + (row & 15);
      *(uint4*)(AsF + rs * 8192 + (fs >> 2) * 2048 + slot * 8) = uw;
    }
  }
  __syncthreads();

  // ---------------- phase 2: MFMA K-loop ----------------
  int sRow = tid >> 2;
  int sKq = tid & 3;
  int sgr = min(rowBase + sRow, N - 1);
  int sSlot = ((sRow >> 4) * 64 + (sKq << 4) + (sRow & 15)) * 8;  // shorts

  f32x4 acc2[4][2];
#pragma unroll
  for (int rg = 0; rg < 4; ++rg) {
    acc2[rg][0] = (f32x4){0.f, 0.f, 0.f, 0.f};
    acc2[rg][1] = (f32x4){0.f, 0.f, 0.f, 0.f};
  }

  const uint4* BpreV = (const uint4*)Bpre;

  for (int kk = 0; kk < 8; ++kk) {
    bool haveX = (kk >= 4);
    uint4 b0 = BpreV[kk * 1024 + tid];
    uint4 b1 = BpreV[kk * 1024 + tid + 256];
    uint4 b2 = BpreV[kk * 1024 + tid + 512];
    uint4 b3 = BpreV[kk * 1024 + tid + 768];
    uint4 uh, ul;
    if (haveX) {
      int kOff = (kk - 4) * 32 + sKq * 8;
      if (mode == 0) {
        float4 p0 = *(const float4*)(Xf + (size_t)sgr * 128 + kOff);
        float4 p1 = *(const float4*)(Xf + (size_t)sgr * 128 + kOff + 4);
        float fv[8] = {p0.x, p0.y, p0.z, p0.w, p1.x, p1.y, p1.z, p1.w};
        unsigned short hh[8], ll[8];
#pragma unroll
        for (int j = 0; j < 8; ++j) {
          unsigned short h = f2bf(fv[j]);
          hh[j] = h;
          ll[j] = f2bf(fv[j] - bf2f(h));
        }
        uh.x = (unsigned)hh[0] | ((unsigned)hh[1] << 16);
        uh.y = (unsigned)hh[2] | ((unsigned)hh[3] << 16);
        uh.z = (unsigned)hh[4] | ((unsigned)hh[5] << 16);
        uh.w = (unsigned)hh[6] | ((unsigned)hh[7] << 16);
        ul.x = (unsigned)ll[0] | ((unsigned)ll[1] << 16);
        ul.y = (unsigned)ll[2] | ((unsigned)ll[3] << 16);
        ul.z = (unsigned)ll[4] | ((unsigned)ll[5] << 16);
        ul.w = (unsigned)ll[6] | ((unsigned)ll[7] << 16);
      } else {
        uh = *(const uint4*)(Xbf + (size_t)sgr * 128 + kOff);
        ul = (uint4){0u, 0u, 0u, 0u};
      }
    }
    __syncthreads();  // previous iteration's Bs/Xs reads done
    uint4* BsV = (uint4*)Bs;
    BsV[tid] = b0;
    BsV[tid + 256] = b1;
    BsV[tid + 512] = b2;
    BsV[tid + 768] = b3;
    if (haveX) {
      *(uint4*)(Xs + sSlot) = uh;
      *(uint4*)(Xs + 2048 + sSlot) = ul;
    }
    __syncthreads();

    int c0 = wv * 2;
    bf16x8 bh0 = *(bf16x8*)(Bs + ((size_t)c0 * 64 + ln) * 8);
    bf16x8 bl0 = *(bf16x8*)(Bs + 4096 + ((size_t)c0 * 64 + ln) * 8);
    bf16x8 bh1 = *(bf16x8*)(Bs + ((size_t)(c0 + 1) * 64 + ln) * 8);
    bf16x8 bl1 = *(bf16x8*)(Bs + 4096 + ((size_t)(c0 + 1) * 64 + ln) * 8);
    const unsigned short* Ahi = haveX ? Xs : (AsF + kk * 2048);
    const unsigned short* Alo = haveX ? (Xs + 2048) : (AsF + 8192 + kk * 2048);
    bool doLo = !(haveX && mode == 1);  // layer-2 self term has lo==0
#pragma unroll
    for (int rg = 0; rg < 4; ++rg) {
      bf16x8 ah = *(bf16x8*)(Ahi + ((size_t)rg * 64 + ln) * 8);
      bf16x8 al = *(bf16x8*)(Alo + ((size_t)rg * 64 + ln) * 8);
      acc2[rg][0] = __builtin_amdgcn_mfma_f32_16x16x32_bf16(ah, bh0, acc2[rg][0], 0, 0, 0);
      acc2[rg][0] = __builtin_amdgcn_mfma_f32_16x16x32_bf16(ah, bl0, acc2[rg][0], 0, 0, 0);
      acc2[rg][1] = __builtin_amdgcn_mfma_f32_16x16x32_bf16(ah, bh1, acc2[rg][1], 0, 0, 0);
      acc2[rg][1] = __builtin_amdgcn_mfma_f32_16x16x32_bf16(ah, bl1, acc2[rg][1], 0, 0, 0);
      if (doLo) {
        acc2[rg][0] = __builtin_amdgcn_mfma_f32_16x16x32_bf16(al, bh0, acc2[rg][0], 0, 0, 0);
        acc2[rg][1] = __builtin_amdgcn_mfma_f32_16x16x32_bf16(al, bh1, acc2[rg][1], 0, 0, 0);
      }
    }
  }

  // epilogue: bias + relu. C layout: col=lane&15, row=(lane>>4)*4+reg (m89).
  int lcol = ln & 15;
  int rsub = (ln >> 4) * 4;
#pragma unroll
  for (int c = 0; c < 2; ++c) {
    float b = bias[(wv * 2 + c) * 16 + lcol];
#pragma unroll
    for (int rg = 0; rg < 4; ++rg)
#pragma unroll
      for (int r = 0; r < 4; ++r) acc2[rg][c][r] = fmaxf(acc2[rg][c][r] + b, 0.f);
  }

  if (mode == 0) {
#pragma unroll
    for (int rg = 0; rg < 4; ++rg)
#pragma unroll
      for (int r = 0; r < 4; ++r) {
        int row = rowBase + rg * 16 + rsub + r;
        if (row < N) {
          OUTbf[(size_t)row * 128 + (wv * 2 + 0) * 16 + lcol] = f2bf(acc2[rg][0][r]);
          OUTbf[(size_t)row * 128 + (wv * 2 + 1) * 16 + lcol] = f2bf(acc2[rg][1][r]);
        }
      }
  } else {
    if (tid < 128) ps[tid] = 0.f;
    __syncthreads();
    int lastRow = min(rowBase + 63, N - 1);
    int g0 = batch[rowBase], g1 = batch[lastRow];
    if (g0 == g1) {
#pragma unroll
      for (int c = 0; c < 2; ++c) {
        float s = 0.f;
#pragma unroll
        for (int rg = 0; rg < 4; ++rg)
#pragma unroll
          for (int r = 0; r < 4; ++r) {
            int row = rowBase + rg * 16 + rsub + r;
            if (row < N) s += acc2[rg][c][r];
          }
        atomicAdd(&ps[(wv * 2 + c) * 16 + lcol], s);
      }
      __syncthreads();
      if (tid < 128) atomicAdd(&gsum[g0 * 128 + tid], ps[tid]);
    } else {
#pragma unroll
      for (int rg = 0; rg < 4; ++rg)
#pragma unroll
        for (int r = 0; r < 4; ++r) {
          int row = rowBase + rg * 16 + rsub + r;
          if (row < N) {
            int g = batch[row];
            atomicAdd(&gsum[g * 128 + (wv * 2 + 0) * 16 + lcol], acc2[rg][0][r]);
            atomicAdd(&gsum[g * 128 + (wv * 2 + 1) * 16 + lcol], acc2[rg][1][r]);
          }
        }
    }
  }
}

// ---- classifier -----------------------------------------------------------

__global__ __launch_bounds__(128) void k_cls1(const float* __restrict__ gsum, const int* __restrict__ gcnt,
                                              const float* __restrict__ Wc1, const float* __restrict__ bc1,
                                              float* __restrict__ z) {
  int g = blockIdx.x;
  int h = threadIdx.x;
  float inv = 1.0f / (float)max(gcnt[g], 1);
  float s = 0.f;
  for (int f = 0; f < 128; ++f) s += gsum[g * 128 + f] * Wc1[h * 128 + f];
  z[g * 128 + h] = fmaxf(s * inv + bc1[h], 0.f);
}

__global__ __launch_bounds__(128) void k_cls2(const float* __restrict__ z, const float* __restrict__ Wc2,
                                              const float* __restrict__ bc2, float* __restrict__ out) {
  __shared__ float red[128];
  int g = blockIdx.x;
  int t = threadIdx.x;
  red[t] = z[g * 128 + t] * Wc2[t];
  __syncthreads();
  for (int d = 64; d > 0; d >>= 1) {
    if (t < d) red[t] += red[t + d];
    __syncthreads();
  }
  if (t == 0) out[g] = red[0] + bc2[0];
}

// ---------------------------------------------------------------------------

extern "C" void kernel_launch(void* const* d_in, const int* in_sizes, int n_in,
                              void* d_out, int out_size, void* d_ws, size_t ws_size,
                              hipStream_t stream) {
  const float* x   = (const float*)d_in[0];
  const int*   ei  = (const int*)d_in[1];
  const int*   bat = (const int*)d_in[2];
  const float* W1l = (const float*)d_in[3];
  const float* b1l = (const float*)d_in[4];
  const float* W1r = (const float*)d_in[5];
  const float* W2l = (const float*)d_in[6];
  const float* b2l = (const float*)d_in[7];
  const float* W2r = (const float*)d_in[8];
  const float* Wc1 = (const float*)d_in[9];
  const float* bc1 = (const float*)d_in[10];
  const float* Wc2 = (const float*)d_in[11];
  const float* bc2 = (const float*)d_in[12];
  float* out = (float*)d_out;

  int N = in_sizes[0] / 128;
  int E = in_sizes[1] / 2;
  int nEblk = (E + HBLK - 1) / HBLK;  // 147
  int nBuk = (N + 255) >> 8;          // 196

  char* ws = (char*)d_ws;
  size_t o = 0;
  auto alloc = [&](size_t bytes) {
    char* p = ws + o;
    o += (bytes + 255) & ~(size_t)255;
    return p;
  };
  int*      off    = (int*)alloc((size_t)(N + 1) * 4);
  int*      col    = (int*)alloc((size_t)E * 4);
  unsigned* ebuk   = (unsigned*)alloc((size_t)E * 4);
  int*      bhist  = (int*)alloc((size_t)nEblk * 256 * 4);
  int*      bukbase= (int*)alloc(257 * 4);
  unsigned short* xbf  = (unsigned short*)alloc((size_t)N * 128 * 2);
  unsigned short* h1bf = (unsigned short*)alloc((size_t)N * 128 * 2);
  unsigned short* Bpre1 = (unsigned short*)alloc(65536 * 2);
  unsigned short* Bpre2 = (unsigned short*)alloc(65536 * 2);
  float*    gsum   = (float*)alloc(64 * 128 * 4 + 64 * 4);
  int*      gcnt   = (int*)(gsum + 64 * 128);
  float*    z      = (float*)alloc(64 * 128 * 4);

  hipMemsetAsync(gsum, 0, 64 * 128 * 4, stream);

  // prep
  k_tobf<<<(N * 128 / 4 + 255) / 256, 256, 0, stream>>>(x, xbf, N * 128);
  k_wprep<<<16, 256, 0, stream>>>(W1l, W1r, Bpre1);
  k_wprep<<<16, 256, 0, stream>>>(W2l, W2r, Bpre2);
  k_gcnt_bs<<<1, 64, 0, stream>>>(bat, gcnt, N, 64);

  // CSR build (counting sort, LDS atomics only)
  k_hist<<<nEblk, 256, 0, stream>>>(ei, bhist, E);
  k_bscan_a<<<1, 256, 0, stream>>>(bhist, bukbase, nEblk);
  k_bscan_b<<<256, 256, 0, stream>>>(bhist, bukbase, nEblk);
  k_scat<<<nEblk, 256, 0, stream>>>(ei, bhist, ebuk, E);
  k_bucket<<<nBuk, 256, 0, stream>>>(ebuk, bukbase, off, col, N, E);

  int nBlk = (N + 63) / 64;
  // layer 1: gather xbf, self-term x (fp32), write h1bf
  k_fused<<<nBlk, 256, 0, stream>>>(xbf, x, nullptr, off, col, Bpre1, b1l,
                                    h1bf, bat, gsum, N, 0);
  // layer 2: gather h1bf, self-term h1bf, pool into gsum
  k_fused<<<nBlk, 256, 0, stream>>>(h1bf, nullptr, h1bf, off, col, Bpre2, b2l,
                                    nullptr, bat, gsum, N, 1);

  // classifier
  k_cls1<<<64, 128, 0, stream>>>(gsum, gcnt, Wc1, bc1, z);
  k_cls2<<<64, 128, 0, stream>>>(z, Wc2, bc2, out);
}

// Round 9
// 191.600 us; speedup vs baseline: 1.6310x; 1.6310x over previous
//
#include <hip/hip_runtime.h>

// ---------------------------------------------------------------------------
// GNN: 2x SAGEConv(mean) + ReLU, global mean pool, 2-layer MLP classifier.
// N=50000 nodes, E=600000 edges, F=H=128, 64 graphs. fp32 in/out.
// R2: hierarchical scan. R3: pool fused into linear epilogue.
// R4: gcnt via binary search. R5: linear -> MFMA bf16x3. R6: bf16 gather.
// R7: CSR via two-level counting sort (LDS atomics only).
// R8 (reverted): agg+lin fusion killed gather TLP (15% occ, 121us).
// R9: R7 structure + R8's keepers: parallel bscan_a/b; h1 bf16-only
//     (layer-2 self term lo=0, skips 2 MFMAs; saves 51MB h1 fp32 traffic).
// ---------------------------------------------------------------------------

typedef __attribute__((ext_vector_type(8))) short bf16x8;
typedef __attribute__((ext_vector_type(8))) unsigned short ushort8;
typedef __attribute__((ext_vector_type(4))) float f32x4;

#define HBLK 4096  // edges per block in the bucket passes

__device__ inline unsigned short f2bf(float f) {
  unsigned u = __float_as_uint(f);
  u += 0x7fff + ((u >> 16) & 1);  // round-to-nearest-even
  return (unsigned short)(u >> 16);
}
__device__ inline float bf2f(unsigned short h) { return __uint_as_float(((unsigned)h) << 16); }

// ---- CSR build: two-level counting sort (no global atomics) ---------------
// Bucket key = dst>>8 (256 buckets covers N<=65536).

__global__ __launch_bounds__(256) void k_hist(const int* __restrict__ ei, int* __restrict__ bhist, int E) {
  __shared__ int h[256];
  int tid = threadIdx.x;
  h[tid] = 0;
  __syncthreads();
  int base = blockIdx.x * HBLK;
  int end = min(base + HBLK, E);
  for (int e = base + tid; e < end; e += 256) {
    int d = ei[E + e];
    atomicAdd(&h[d >> 8], 1);
  }
  __syncthreads();
  bhist[blockIdx.x * 256 + tid] = h[tid];
}

// bucket totals + exclusive scan -> bukbase[257]
__global__ __launch_bounds__(256) void k_bscan_a(const int* __restrict__ bhist, int* __restrict__ bukbase,
                                                 int nblk) {
  __shared__ int s[256];
  int t = threadIdx.x;
  int sum = 0;
  for (int b = 0; b < nblk; ++b) sum += bhist[b * 256 + t];  // coalesced, independent
  s[t] = sum;
  __syncthreads();
  for (int d = 1; d < 256; d <<= 1) {
    int v = (t >= d) ? s[t - d] : 0;
    __syncthreads();
    s[t] += v;
    __syncthreads();
  }
  bukbase[t] = s[t] - sum;  // exclusive
  if (t == 255) bukbase[256] = s[255];
}

// per-bucket scan over blocks: bhist[b][buk] = bukbase[buk] + prefix_{b'<b}
__global__ __launch_bounds__(256) void k_bscan_b(int* __restrict__ bhist, const int* __restrict__ bukbase,
                                                 int nblk) {
  __shared__ int s[256];
  int buk = blockIdx.x;
  int t = threadIdx.x;
  int c = (t < nblk) ? bhist[t * 256 + buk] : 0;
  s[t] = c;
  __syncthreads();
  for (int d = 1; d < 256; d <<= 1) {
    int v = (t >= d) ? s[t - d] : 0;
    __syncthreads();
    s[t] += v;
    __syncthreads();
  }
  if (t < nblk) bhist[t * 256 + buk] = bukbase[buk] + s[t] - c;
}

// scatter edges into bucket order, packed (dstLow8<<24 | src)
__global__ __launch_bounds__(256) void k_scat(const int* __restrict__ ei, const int* __restrict__ bhist,
                                              unsigned* __restrict__ ebuk, int E) {
  __shared__ int cur[256];
  int tid = threadIdx.x;
  cur[tid] = bhist[blockIdx.x * 256 + tid];
  __syncthreads();
  int base = blockIdx.x * HBLK;
  int end = min(base + HBLK, E);
  for (int e = base + tid; e < end; e += 256) {
    int d = ei[E + e];
    int srcv = ei[e];
    int p = atomicAdd(&cur[d >> 8], 1);
    ebuk[p] = ((unsigned)(d & 255) << 24) | (unsigned)srcv;
  }
}

// per-bucket local counting sort -> off (coalesced) + col
__global__ __launch_bounds__(256) void k_bucket(const unsigned* __restrict__ ebuk,
                                                const int* __restrict__ bukbase,
                                                int* __restrict__ off, int* __restrict__ colv,
                                                int N, int E) {
  __shared__ int h[256];
  __shared__ int cur[256];
  __shared__ int sc[256];
  int tid = threadIdx.x;
  int buk = blockIdx.x;
  int b0 = bukbase[buk], b1 = bukbase[buk + 1];
  h[tid] = 0;
  __syncthreads();
  for (int i = b0 + tid; i < b1; i += 256) atomicAdd(&h[ebuk[i] >> 24], 1);
  __syncthreads();
  int my = h[tid];
  sc[tid] = my;
  __syncthreads();
  for (int d = 1; d < 256; d <<= 1) {
    int v = (tid >= d) ? sc[tid - d] : 0;
    __syncthreads();
    sc[tid] += v;
    __syncthreads();
  }
  int excl = sc[tid] - my;
  cur[tid] = excl;
  int node = buk * 256 + tid;
  if (node < N) off[node] = b0 + excl;
  if (buk == gridDim.x - 1 && tid == 0) off[N] = E;
  __syncthreads();
  for (int i = b0 + tid; i < b1; i += 256) {
    unsigned v = ebuk[i];
    int p = atomicAdd(&cur[v >> 24], 1);
    colv[b0 + p] = (int)(v & 0xFFFFFFu);
  }
}

// ---- gcnt via binary search on sorted batch -------------------------------

__global__ __launch_bounds__(64) void k_gcnt_bs(const int* __restrict__ batch, int* __restrict__ gcnt,
                                                int N, int G) {
  int g = threadIdx.x;
  if (g >= G) return;
  int lo = 0, hi = N;
  while (lo < hi) { int mid = (lo + hi) >> 1; if (batch[mid] < g) lo = mid + 1; else hi = mid; }
  int a = lo;
  lo = 0; hi = N;
  while (lo < hi) { int mid = (lo + hi) >> 1; if (batch[mid] < g + 1) lo = mid + 1; else hi = mid; }
  gcnt[g] = lo - a;
}

// ---- fp32 -> bf16 convert (gather source) ---------------------------------

__global__ __launch_bounds__(256) void k_tobf(const float* __restrict__ x,
                                              unsigned short* __restrict__ xbf, int total) {
  int i = (blockIdx.x * 256 + threadIdx.x) * 4;
  if (i + 3 < total) {
    float4 v = *(const float4*)(x + i);
    ushort4 p;
    p.x = f2bf(v.x); p.y = f2bf(v.y); p.z = f2bf(v.z); p.w = f2bf(v.w);
    *(ushort4*)(xbf + i) = p;
  } else {
    for (int k = 0; k < 4 && i + k < total; ++k) xbf[i + k] = f2bf(x[i + k]);
  }
}

// ---- mean aggregation (bf16 source), fp32 output --------------------------

__global__ __launch_bounds__(256) void k_agg_bf(const unsigned short* __restrict__ Xbf,
                                                const int* __restrict__ off, const int* __restrict__ col,
                                                float* __restrict__ T, int N) {
  int wid = (blockIdx.x * 256 + threadIdx.x) >> 6;
  int ln = threadIdx.x & 63;
  if (wid >= N) return;
  int o0 = off[wid], o1 = off[wid + 1];
  int deg = o1 - o0;
  int rs = ln >> 4, fs = ln & 15;
  float acc[8];
#pragma unroll
  for (int j = 0; j < 8; ++j) acc[j] = 0.f;

  for (int base = 0; base < deg; base += 16) {
#pragma unroll
    for (int u = 0; u < 4; ++u) {
      int n = base + u * 4 + rs;
      if (n < deg) {
        int idx = col[o0 + n];
        ushort8 q = *(const ushort8*)(Xbf + (size_t)idx * 128 + fs * 8);
#pragma unroll
        for (int j = 0; j < 8; ++j) acc[j] += bf2f(q[j]);
      }
    }
  }
#pragma unroll
  for (int j = 0; j < 8; ++j) {
    acc[j] += __shfl_xor(acc[j], 16);
    acc[j] += __shfl_xor(acc[j], 32);
  }
  if (rs == 0) {
    float sc = 1.0f / (float)max(deg, 1);
    float4 r0 = {acc[0] * sc, acc[1] * sc, acc[2] * sc, acc[3] * sc};
    float4 r1 = {acc[4] * sc, acc[5] * sc, acc[6] * sc, acc[7] * sc};
    *(float4*)(T + (size_t)wid * 128 + fs * 8) = r0;
    *(float4*)(T + (size_t)wid * 128 + fs * 8 + 4) = r1;
  }
}

// ---- weight prep: split fp32 W into bf16 hi/lo, fragment-linear -----------
// Bpre layout: [kk 8][half 2][ct 8][lane 64][j 8] bf16 (65536 shorts = 128KB)

__global__ __launch_bounds__(256) void k_wprep(const float* __restrict__ Wl, const float* __restrict__ Wr,
                                               unsigned short* __restrict__ Bpre) {
  int id = blockIdx.x * 256 + threadIdx.x;  // 4096 slots
  if (id >= 4096) return;
  int kk = id >> 9;
  int ct = (id >> 6) & 7;
  int l  = id & 63;
  int colIdx = ct * 16 + (l & 15);
  int k0 = kk * 32 + (l >> 4) * 8;
  const float* W = (k0 < 128) ? Wl : Wr;
  int kb = k0 & 127;
#pragma unroll
  for (int j = 0; j < 8; ++j) {
    float v = W[colIdx * 128 + kb + j];
    unsigned short h = f2bf(v);
    size_t bh = (size_t)kk * 8192 + ((size_t)ct * 64 + l) * 8 + j;
    Bpre[bh] = h;
    Bpre[bh + 4096] = f2bf(v - bf2f(h));
  }
}

// ---- MFMA fused linear: H = relu([A|X] @ [Wl;Wr].T + b) -------------------
// A = agg result fp32 (split hi/lo in-kernel). Self term X:
//   mode 0 (layer 1): Xf fp32 (full hi/lo, 6 MFMA/kk); OUTbf written (h1 bf16).
//   mode 1 (layer 2): Xbf bf16 (lo=0, 4 MFMA/kk); pool into gsum.

__global__ __launch_bounds__(256) void k_lin_mfma(
    const float* __restrict__ A,
    const float* __restrict__ Xf,
    const unsigned short* __restrict__ Xbf,
    const unsigned short* __restrict__ Bpre,
    const float* __restrict__ bias,
    unsigned short* __restrict__ OUTbf,
    const int* __restrict__ batch, float* __restrict__ gsum,
    int N, int mode) {
  __shared__ unsigned short As[4096];  // [half 2][rowgrp 4][lane 64][8]  8KB
  __shared__ unsigned short Bs[8192];  // [half 2][ct 8][lane 64][8]     16KB
  __shared__ float ps[128];

  int tid = threadIdx.x;
  int wv = tid >> 6, ln = tid & 63;
  int rowBase = blockIdx.x * 64;

  int sRow = tid >> 2;
  int sKq = tid & 3;
  int sgr = min(rowBase + sRow, N - 1);
  int sSlot = ((sRow >> 4) * 64 + (sKq << 4) + (sRow & 15)) * 8;  // shorts

  f32x4 acc[4][2];
#pragma unroll
  for (int rg = 0; rg < 4; ++rg) {
    acc[rg][0] = (f32x4){0.f, 0.f, 0.f, 0.f};
    acc[rg][1] = (f32x4){0.f, 0.f, 0.f, 0.f};
  }

  const uint4* BpreV = (const uint4*)Bpre;

  for (int kk = 0; kk < 8; ++kk) {
    bool selfTerm = (kk >= 4);
    int kOff = (kk & 3) * 32 + sKq * 8;
    uint4 b0 = BpreV[kk * 1024 + tid];
    uint4 b1 = BpreV[kk * 1024 + tid + 256];
    uint4 b2 = BpreV[kk * 1024 + tid + 512];
    uint4 b3 = BpreV[kk * 1024 + tid + 768];

    uint4 uh, ul;
    bool bf16Self = selfTerm && (mode == 1);
    if (bf16Self) {
      uh = *(const uint4*)(Xbf + (size_t)sgr * 128 + kOff);
      ul = (uint4){0u, 0u, 0u, 0u};
    } else {
      const float* S = selfTerm ? Xf : A;
      float4 p0 = *(const float4*)(S + (size_t)sgr * 128 + kOff);
      float4 p1 = *(const float4*)(S + (size_t)sgr * 128 + kOff + 4);
      float fv[8] = {p0.x, p0.y, p0.z, p0.w, p1.x, p1.y, p1.z, p1.w};
      unsigned short hh[8], ll[8];
#pragma unroll
      for (int j = 0; j < 8; ++j) {
        unsigned short h = f2bf(fv[j]);
        hh[j] = h;
        ll[j] = f2bf(fv[j] - bf2f(h));
      }
      uh.x = (unsigned)hh[0] | ((unsigned)hh[1] << 16);
      uh.y = (unsigned)hh[2] | ((unsigned)hh[3] << 16);
      uh.z = (unsigned)hh[4] | ((unsigned)hh[5] << 16);
      uh.w = (unsigned)hh[6] | ((unsigned)hh[7] << 16);
      ul.x = (unsigned)ll[0] | ((unsigned)ll[1] << 16);
      ul.y = (unsigned)ll[2] | ((unsigned)ll[3] << 16);
      ul.z = (unsigned)ll[4] | ((unsigned)ll[5] << 16);
      ul.w = (unsigned)ll[6] | ((unsigned)ll[7] << 16);
    }

    __syncthreads();  // previous iteration's reads done
    *(uint4*)(As + sSlot) = uh;
    *(uint4*)(As + 2048 + sSlot) = ul;
    uint4* BsV = (uint4*)Bs;
    BsV[tid] = b0;
    BsV[tid + 256] = b1;
    BsV[tid + 512] = b2;
    BsV[tid + 768] = b3;
    __syncthreads();

    int c0 = wv * 2;
    bf16x8 bh0 = *(bf16x8*)(Bs + ((size_t)c0 * 64 + ln) * 8);
    bf16x8 bl0 = *(bf16x8*)(Bs + 4096 + ((size_t)c0 * 64 + ln) * 8);
    bf16x8 bh1 = *(bf16x8*)(Bs + ((size_t)(c0 + 1) * 64 + ln) * 8);
    bf16x8 bl1 = *(bf16x8*)(Bs + 4096 + ((size_t)(c0 + 1) * 64 + ln) * 8);
    bool doLo = !bf16Self;
#pragma unroll
    for (int rg = 0; rg < 4; ++rg) {
      bf16x8 ah = *(bf16x8*)(As + ((size_t)rg * 64 + ln) * 8);
      bf16x8 al = *(bf16x8*)(As + 2048 + ((size_t)rg * 64 + ln) * 8);
      acc[rg][0] = __builtin_amdgcn_mfma_f32_16x16x32_bf16(ah, bh0, acc[rg][0], 0, 0, 0);
      acc[rg][0] = __builtin_amdgcn_mfma_f32_16x16x32_bf16(ah, bl0, acc[rg][0], 0, 0, 0);
      acc[rg][1] = __builtin_amdgcn_mfma_f32_16x16x32_bf16(ah, bh1, acc[rg][1], 0, 0, 0);
      acc[rg][1] = __builtin_amdgcn_mfma_f32_16x16x32_bf16(ah, bl1, acc[rg][1], 0, 0, 0);
      if (doLo) {
        acc[rg][0] = __builtin_amdgcn_mfma_f32_16x16x32_bf16(al, bh0, acc[rg][0], 0, 0, 0);
        acc[rg][1] = __builtin_amdgcn_mfma_f32_16x16x32_bf16(al, bh1, acc[rg][1], 0, 0, 0);
      }
    }
  }

  // epilogue: bias + relu. C layout: col=lane&15, row=(lane>>4)*4+reg (m89).
  int lcol = ln & 15;
  int rsub = (ln >> 4) * 4;
#pragma unroll
  for (int c = 0; c < 2; ++c) {
    float b = bias[(wv * 2 + c) * 16 + lcol];
#pragma unroll
    for (int rg = 0; rg < 4; ++rg)
#pragma unroll
      for (int r = 0; r < 4; ++r) acc[rg][c][r] = fmaxf(acc[rg][c][r] + b, 0.f);
  }

  if (mode == 0) {
#pragma unroll
    for (int rg = 0; rg < 4; ++rg)
#pragma unroll
      for (int r = 0; r < 4; ++r) {
        int row = rowBase + rg * 16 + rsub + r;
        if (row < N) {
          OUTbf[(size_t)row * 128 + (wv * 2 + 0) * 16 + lcol] = f2bf(acc[rg][0][r]);
          OUTbf[(size_t)row * 128 + (wv * 2 + 1) * 16 + lcol] = f2bf(acc[rg][1][r]);
        }
      }
  } else {
    if (tid < 128) ps[tid] = 0.f;
    __syncthreads();
    int lastRow = min(rowBase + 63, N - 1);
    int g0 = batch[rowBase], g1 = batch[lastRow];
    if (g0 == g1) {
#pragma unroll
      for (int c = 0; c < 2; ++c) {
        float s = 0.f;
#pragma unroll
        for (int rg = 0; rg < 4; ++rg)
#pragma unroll
          for (int r = 0; r < 4; ++r) {
            int row = rowBase + rg * 16 + rsub + r;
            if (row < N) s += acc[rg][c][r];
          }
        atomicAdd(&ps[(wv * 2 + c) * 16 + lcol], s);
      }
      __syncthreads();
      if (tid < 128) atomicAdd(&gsum[g0 * 128 + tid], ps[tid]);
    } else {
#pragma unroll
      for (int rg = 0; rg < 4; ++rg)
#pragma unroll
        for (int r = 0; r < 4; ++r) {
          int row = rowBase + rg * 16 + rsub + r;
          if (row < N) {
            int g = batch[row];
            atomicAdd(&gsum[g * 128 + (wv * 2 + 0) * 16 + lcol], acc[rg][0][r]);
            atomicAdd(&gsum[g * 128 + (wv * 2 + 1) * 16 + lcol], acc[rg][1][r]);
          }
        }
    }
  }
}

// ---- classifier -----------------------------------------------------------

__global__ __launch_bounds__(128) void k_cls1(const float* __restrict__ gsum, const int* __restrict__ gcnt,
                                              const float* __restrict__ Wc1, const float* __restrict__ bc1,
                                              float* __restrict__ z) {
  int g = blockIdx.x;
  int h = threadIdx.x;
  float inv = 1.0f / (float)max(gcnt[g], 1);
  float s = 0.f;
  for (int f = 0; f < 128; ++f) s += gsum[g * 128 + f] * Wc1[h * 128 + f];
  z[g * 128 + h] = fmaxf(s * inv + bc1[h], 0.f);
}

__global__ __launch_bounds__(128) void k_cls2(const float* __restrict__ z, const float* __restrict__ Wc2,
                                              const float* __restrict__ bc2, float* __restrict__ out) {
  __shared__ float red[128];
  int g = blockIdx.x;
  int t = threadIdx.x;
  red[t] = z[g * 128 + t] * Wc2[t];
  __syncthreads();
  for (int d = 64; d > 0; d >>= 1) {
    if (t < d) red[t] += red[t + d];
    __syncthreads();
  }
  if (t == 0) out[g] = red[0] + bc2[0];
}

// ---------------------------------------------------------------------------

extern "C" void kernel_launch(void* const* d_in, const int* in_sizes, int n_in,
                              void* d_out, int out_size, void* d_ws, size_t ws_size,
                              hipStream_t stream) {
  const float* x   = (const float*)d_in[0];
  const int*   ei  = (const int*)d_in[1];
  const int*   bat = (const int*)d_in[2];
  const float* W1l = (const float*)d_in[3];
  const float* b1l = (const float*)d_in[4];
  const float* W1r = (const float*)d_in[5];
  const float* W2l = (const float*)d_in[6];
  const float* b2l = (const float*)d_in[7];
  const float* W2r = (const float*)d_in[8];
  const float* Wc1 = (const float*)d_in[9];
  const float* bc1 = (const float*)d_in[10];
  const float* Wc2 = (const float*)d_in[11];
  const float* bc2 = (const float*)d_in[12];
  float* out = (float*)d_out;

  int N = in_sizes[0] / 128;
  int E = in_sizes[1] / 2;
  int nEblk = (E + HBLK - 1) / HBLK;  // 147
  int nBuk = (N + 255) >> 8;          // 196

  char* ws = (char*)d_ws;
  size_t o = 0;
  auto alloc = [&](size_t bytes) {
    char* p = ws + o;
    o += (bytes + 255) & ~(size_t)255;
    return p;
  };
  int*      off    = (int*)alloc((size_t)(N + 1) * 4);
  int*      col    = (int*)alloc((size_t)E * 4);
  unsigned* ebuk   = (unsigned*)alloc((size_t)E * 4);
  int*      bhist  = (int*)alloc((size_t)nEblk * 256 * 4);
  int*      bukbase= (int*)alloc(257 * 4);
  float*    T      = (float*)alloc((size_t)N * 128 * 4);
  unsigned short* xbf  = (unsigned short*)alloc((size_t)N * 128 * 2);
  unsigned short* h1bf = (unsigned short*)alloc((size_t)N * 128 * 2);
  unsigned short* Bpre1 = (unsigned short*)alloc(65536 * 2);
  unsigned short* Bpre2 = (unsigned short*)alloc(65536 * 2);
  float*    gsum   = (float*)alloc(64 * 128 * 4 + 64 * 4);
  int*      gcnt   = (int*)(gsum + 64 * 128);
  float*    z      = (float*)alloc(64 * 128 * 4);

  hipMemsetAsync(gsum, 0, 64 * 128 * 4, stream);

  // prep
  k_tobf<<<(N * 128 / 4 + 255) / 256, 256, 0, stream>>>(x, xbf, N * 128);
  k_wprep<<<16, 256, 0, stream>>>(W1l, W1r, Bpre1);
  k_wprep<<<16, 256, 0, stream>>>(W2l, W2r, Bpre2);
  k_gcnt_bs<<<1, 64, 0, stream>>>(bat, gcnt, N, 64);

  // CSR build (counting sort, LDS atomics only)
  k_hist<<<nEblk, 256, 0, stream>>>(ei, bhist, E);
  k_bscan_a<<<1, 256, 0, stream>>>(bhist, bukbase, nEblk);
  k_bscan_b<<<256, 256, 0, stream>>>(bhist, bukbase, nEblk);
  k_scat<<<nEblk, 256, 0, stream>>>(ei, bhist, ebuk, E);
  k_bucket<<<nBuk, 256, 0, stream>>>(ebuk, bukbase, off, col, N, E);

  int nLinBlk = (N + 63) / 64;
  // layer 1: agg(xbf) -> T; lin(T, x fp32) -> h1bf
  k_agg_bf<<<(N + 3) / 4, 256, 0, stream>>>(xbf, off, col, T, N);
  k_lin_mfma<<<nLinBlk, 256, 0, stream>>>(T, x, nullptr, Bpre1, b1l, h1bf, bat, gsum, N, 0);
  // layer 2: agg(h1bf) -> T; lin(T, h1bf) -> pooled gsum
  k_agg_bf<<<(N + 3) / 4, 256, 0, stream>>>(h1bf, off, col, T, N);
  k_lin_mfma<<<nLinBlk, 256, 0, stream>>>(T, nullptr, h1bf, Bpre2, b2l, nullptr, bat, gsum, N, 1);

  // classifier
  k_cls1<<<64, 128, 0, stream>>>(gsum, gcnt, Wc1, bc1, z);
  k_cls2<<<64, 128, 0, stream>>>(z, Wc2, bc2, out);
}

// Round 10
// 168.532 us; speedup vs baseline: 1.8542x; 1.1369x over previous
//
#include <hip/hip_runtime.h>

// ---------------------------------------------------------------------------
// GNN: 2x SAGEConv(mean) + ReLU, global mean pool, 2-layer MLP classifier.
// N=50000 nodes, E=600000 edges, F=H=128, 64 graphs. fp32 in/out.
// R2: hierarchical scan. R3: pool fused into linear epilogue.
// R4: gcnt via binary search. R5: linear -> MFMA bf16x3. R6: bf16 gather.
// R7: CSR via two-level counting sort. R8 (reverted): fusion killed TLP.
// R9: h1 bf16-only. R10: T bf16 (saves 38MB/layer, agg-term 4 MFMA/kk);
//     dispatch diet: prep kernels fused into k_prep block ranges, cls1+cls2
//     fused, memset folded in (16 -> 10 dispatches).
// ---------------------------------------------------------------------------

typedef __attribute__((ext_vector_type(8))) short bf16x8;
typedef __attribute__((ext_vector_type(8))) unsigned short ushort8;
typedef __attribute__((ext_vector_type(4))) float f32x4;

#define HBLK 4096  // edges per block in the bucket passes

__device__ inline unsigned short f2bf(float f) {
  unsigned u = __float_as_uint(f);
  u += 0x7fff + ((u >> 16) & 1);  // round-to-nearest-even
  return (unsigned short)(u >> 16);
}
__device__ inline float bf2f(unsigned short h) { return __uint_as_float(((unsigned)h) << 16); }

// ---- fused prep: tobf | wprep(W1) | wprep(W2) | hist | {gcnt + gsum=0} ----
// All parts independent; selected by block range (block-uniform branches).

__device__ inline void wprep_body(int id, const float* __restrict__ Wl, const float* __restrict__ Wr,
                                  unsigned short* __restrict__ Bpre) {
  // Bpre layout: [kk 8][half 2][ct 8][lane 64][j 8] bf16
  if (id >= 4096) return;
  int kk = id >> 9;
  int ct = (id >> 6) & 7;
  int l  = id & 63;
  int colIdx = ct * 16 + (l & 15);
  int k0 = kk * 32 + (l >> 4) * 8;
  const float* W = (k0 < 128) ? Wl : Wr;
  int kb = k0 & 127;
#pragma unroll
  for (int j = 0; j < 8; ++j) {
    float v = W[colIdx * 128 + kb + j];
    unsigned short h = f2bf(v);
    size_t bh = (size_t)kk * 8192 + ((size_t)ct * 64 + l) * 8 + j;
    Bpre[bh] = h;
    Bpre[bh + 4096] = f2bf(v - bf2f(h));
  }
}

__global__ __launch_bounds__(256) void k_prep(
    const float* __restrict__ x, unsigned short* __restrict__ xbf, int total,
    const float* __restrict__ W1l, const float* __restrict__ W1r, unsigned short* __restrict__ Bpre1,
    const float* __restrict__ W2l, const float* __restrict__ W2r, unsigned short* __restrict__ Bpre2,
    const int* __restrict__ batch, int* __restrict__ gcnt, float* __restrict__ gsum, int N,
    const int* __restrict__ ei, int* __restrict__ bhist, int E,
    int nTobf, int nEblk) {
  __shared__ int h[256];
  int b = blockIdx.x;
  int tid = threadIdx.x;
  if (b < nTobf) {
    int i = (b * 256 + tid) * 4;
    if (i + 3 < total) {
      float4 v = *(const float4*)(x + i);
      ushort4 p;
      p.x = f2bf(v.x); p.y = f2bf(v.y); p.z = f2bf(v.z); p.w = f2bf(v.w);
      *(ushort4*)(xbf + i) = p;
    } else {
      for (int k = 0; k < 4 && i + k < total; ++k) xbf[i + k] = f2bf(x[i + k]);
    }
  } else if (b < nTobf + 16) {
    wprep_body((b - nTobf) * 256 + tid, W1l, W1r, Bpre1);
  } else if (b < nTobf + 32) {
    wprep_body((b - nTobf - 16) * 256 + tid, W2l, W2r, Bpre2);
  } else if (b < nTobf + 32 + nEblk) {
    int eb = b - nTobf - 32;
    h[tid] = 0;
    __syncthreads();
    int base = eb * HBLK;
    int end = min(base + HBLK, E);
    for (int e = base + tid; e < end; e += 256) atomicAdd(&h[ei[E + e] >> 8], 1);
    __syncthreads();
    bhist[eb * 256 + tid] = h[tid];
  } else {
    for (int i = tid; i < 64 * 128; i += 256) gsum[i] = 0.f;
    if (tid < 64) {
      int g = tid;
      int lo = 0, hi = N;
      while (lo < hi) { int mid = (lo + hi) >> 1; if (batch[mid] < g) lo = mid + 1; else hi = mid; }
      int a = lo;
      lo = 0; hi = N;
      while (lo < hi) { int mid = (lo + hi) >> 1; if (batch[mid] < g + 1) lo = mid + 1; else hi = mid; }
      gcnt[g] = lo - a;
    }
  }
}

// ---- CSR build (rest of counting sort) ------------------------------------

__global__ __launch_bounds__(256) void k_bscan_a(const int* __restrict__ bhist, int* __restrict__ bukbase,
                                                 int nblk) {
  __shared__ int s[256];
  int t = threadIdx.x;
  int sum = 0;
  for (int b = 0; b < nblk; ++b) sum += bhist[b * 256 + t];
  s[t] = sum;
  __syncthreads();
  for (int d = 1; d < 256; d <<= 1) {
    int v = (t >= d) ? s[t - d] : 0;
    __syncthreads();
    s[t] += v;
    __syncthreads();
  }
  bukbase[t] = s[t] - sum;
  if (t == 255) bukbase[256] = s[255];
}

__global__ __launch_bounds__(256) void k_bscan_b(int* __restrict__ bhist, const int* __restrict__ bukbase,
                                                 int nblk) {
  __shared__ int s[256];
  int buk = blockIdx.x;
  int t = threadIdx.x;
  int c = (t < nblk) ? bhist[t * 256 + buk] : 0;
  s[t] = c;
  __syncthreads();
  for (int d = 1; d < 256; d <<= 1) {
    int v = (t >= d) ? s[t - d] : 0;
    __syncthreads();
    s[t] += v;
    __syncthreads();
  }
  if (t < nblk) bhist[t * 256 + buk] = bukbase[buk] + s[t] - c;
}

__global__ __launch_bounds__(256) void k_scat(const int* __restrict__ ei, const int* __restrict__ bhist,
                                              unsigned* __restrict__ ebuk, int E) {
  __shared__ int cur[256];
  int tid = threadIdx.x;
  cur[tid] = bhist[blockIdx.x * 256 + tid];
  __syncthreads();
  int base = blockIdx.x * HBLK;
  int end = min(base + HBLK, E);
  for (int e = base + tid; e < end; e += 256) {
    int d = ei[E + e];
    int srcv = ei[e];
    int p = atomicAdd(&cur[d >> 8], 1);
    ebuk[p] = ((unsigned)(d & 255) << 24) | (unsigned)srcv;
  }
}

__global__ __launch_bounds__(256) void k_bucket(const unsigned* __restrict__ ebuk,
                                                const int* __restrict__ bukbase,
                                                int* __restrict__ off, int* __restrict__ colv,
                                                int N, int E) {
  __shared__ int h[256];
  __shared__ int cur[256];
  __shared__ int sc[256];
  int tid = threadIdx.x;
  int buk = blockIdx.x;
  int b0 = bukbase[buk], b1 = bukbase[buk + 1];
  h[tid] = 0;
  __syncthreads();
  for (int i = b0 + tid; i < b1; i += 256) atomicAdd(&h[ebuk[i] >> 24], 1);
  __syncthreads();
  int my = h[tid];
  sc[tid] = my;
  __syncthreads();
  for (int d = 1; d < 256; d <<= 1) {
    int v = (tid >= d) ? sc[tid - d] : 0;
    __syncthreads();
    sc[tid] += v;
    __syncthreads();
  }
  int excl = sc[tid] - my;
  cur[tid] = excl;
  int node = buk * 256 + tid;
  if (node < N) off[node] = b0 + excl;
  if (buk == gridDim.x - 1 && tid == 0) off[N] = E;
  __syncthreads();
  for (int i = b0 + tid; i < b1; i += 256) {
    unsigned v = ebuk[i];
    int p = atomicAdd(&cur[v >> 24], 1);
    colv[b0 + p] = (int)(v & 0xFFFFFFu);
  }
}

// ---- mean aggregation (bf16 source -> bf16 output) ------------------------

__global__ __launch_bounds__(256) void k_agg_bf(const unsigned short* __restrict__ Xbf,
                                                const int* __restrict__ off, const int* __restrict__ col,
                                                unsigned short* __restrict__ Tbf, int N) {
  int wid = (blockIdx.x * 256 + threadIdx.x) >> 6;
  int ln = threadIdx.x & 63;
  if (wid >= N) return;
  int o0 = off[wid], o1 = off[wid + 1];
  int deg = o1 - o0;
  int rs = ln >> 4, fs = ln & 15;
  float acc[8];
#pragma unroll
  for (int j = 0; j < 8; ++j) acc[j] = 0.f;

  for (int base = 0; base < deg; base += 16) {
#pragma unroll
    for (int u = 0; u < 4; ++u) {
      int n = base + u * 4 + rs;
      if (n < deg) {
        int idx = col[o0 + n];
        ushort8 q = *(const ushort8*)(Xbf + (size_t)idx * 128 + fs * 8);
#pragma unroll
        for (int j = 0; j < 8; ++j) acc[j] += bf2f(q[j]);
      }
    }
  }
#pragma unroll
  for (int j = 0; j < 8; ++j) {
    acc[j] += __shfl_xor(acc[j], 16);
    acc[j] += __shfl_xor(acc[j], 32);
  }
  if (rs == 0) {
    float sc = 1.0f / (float)max(deg, 1);
    unsigned short w[8];
#pragma unroll
    for (int j = 0; j < 8; ++j) w[j] = f2bf(acc[j] * sc);
    uint4 uw;
    uw.x = (unsigned)w[0] | ((unsigned)w[1] << 16);
    uw.y = (unsigned)w[2] | ((unsigned)w[3] << 16);
    uw.z = (unsigned)w[4] | ((unsigned)w[5] << 16);
    uw.w = (unsigned)w[6] | ((unsigned)w[7] << 16);
    *(uint4*)(Tbf + (size_t)wid * 128 + fs * 8) = uw;
  }
}

// ---- MFMA fused linear: H = relu([T|X] @ [Wl;Wr].T + b) -------------------
// Agg term T: bf16 (lo=0, 4 MFMA/kk). Self term X:
//   mode 0 (layer 1): Xf fp32 (hi/lo, 6 MFMA/kk); writes OUTbf (h1 bf16).
//   mode 1 (layer 2): Xbf bf16 (4 MFMA/kk); pools into gsum.

__global__ __launch_bounds__(256) void k_lin_mfma(
    const unsigned short* __restrict__ Tbf,
    const float* __restrict__ Xf,
    const unsigned short* __restrict__ Xbf,
    const unsigned short* __restrict__ Bpre,
    const float* __restrict__ bias,
    unsigned short* __restrict__ OUTbf,
    const int* __restrict__ batch, float* __restrict__ gsum,
    int N, int mode) {
  __shared__ unsigned short As[4096];  // [half 2][rowgrp 4][lane 64][8]  8KB
  __shared__ unsigned short Bs[8192];  // [half 2][ct 8][lane 64][8]     16KB
  __shared__ float ps[128];

  int tid = threadIdx.x;
  int wv = tid >> 6, ln = tid & 63;
  int rowBase = blockIdx.x * 64;

  int sRow = tid >> 2;
  int sKq = tid & 3;
  int sgr = min(rowBase + sRow, N - 1);
  int sSlot = ((sRow >> 4) * 64 + (sKq << 4) + (sRow & 15)) * 8;  // shorts

  f32x4 acc[4][2];
#pragma unroll
  for (int rg = 0; rg < 4; ++rg) {
    acc[rg][0] = (f32x4){0.f, 0.f, 0.f, 0.f};
    acc[rg][1] = (f32x4){0.f, 0.f, 0.f, 0.f};
  }

  const uint4* BpreV = (const uint4*)Bpre;

  for (int kk = 0; kk < 8; ++kk) {
    bool selfTerm = (kk >= 4);
    int kOff = (kk & 3) * 32 + sKq * 8;
    uint4 b0 = BpreV[kk * 1024 + tid];
    uint4 b1 = BpreV[kk * 1024 + tid + 256];
    uint4 b2 = BpreV[kk * 1024 + tid + 512];
    uint4 b3 = BpreV[kk * 1024 + tid + 768];

    uint4 uh = {0u, 0u, 0u, 0u}, ul = {0u, 0u, 0u, 0u};
    bool doLo = selfTerm && (mode == 0);
    if (!selfTerm) {
      uh = *(const uint4*)(Tbf + (size_t)sgr * 128 + kOff);
    } else if (mode == 1) {
      uh = *(const uint4*)(Xbf + (size_t)sgr * 128 + kOff);
    } else {
      float4 p0 = *(const float4*)(Xf + (size_t)sgr * 128 + kOff);
      float4 p1 = *(const float4*)(Xf + (size_t)sgr * 128 + kOff + 4);
      float fv[8] = {p0.x, p0.y, p0.z, p0.w, p1.x, p1.y, p1.z, p1.w};
      unsigned short hh[8], ll[8];
#pragma unroll
      for (int j = 0; j < 8; ++j) {
        unsigned short h = f2bf(fv[j]);
        hh[j] = h;
        ll[j] = f2bf(fv[j] - bf2f(h));
      }
      uh.x = (unsigned)hh[0] | ((unsigned)hh[1] << 16);
      uh.y = (unsigned)hh[2] | ((unsigned)hh[3] << 16);
      uh.z = (unsigned)hh[4] | ((unsigned)hh[5] << 16);
      uh.w = (unsigned)hh[6] | ((unsigned)hh[7] << 16);
      ul.x = (unsigned)ll[0] | ((unsigned)ll[1] << 16);
      ul.y = (unsigned)ll[2] | ((unsigned)ll[3] << 16);
      ul.z = (unsigned)ll[4] | ((unsigned)ll[5] << 16);
      ul.w = (unsigned)ll[6] | ((unsigned)ll[7] << 16);
    }

    __syncthreads();  // previous iteration's reads done
    *(uint4*)(As + sSlot) = uh;
    if (doLo) *(uint4*)(As + 2048 + sSlot) = ul;
    uint4* BsV = (uint4*)Bs;
    BsV[tid] = b0;
    BsV[tid + 256] = b1;
    BsV[tid + 512] = b2;
    BsV[tid + 768] = b3;
    __syncthreads();

    int c0 = wv * 2;
    bf16x8 bh0 = *(bf16x8*)(Bs + ((size_t)c0 * 64 + ln) * 8);
    bf16x8 bl0 = *(bf16x8*)(Bs + 4096 + ((size_t)c0 * 64 + ln) * 8);
    bf16x8 bh1 = *(bf16x8*)(Bs + ((size_t)(c0 + 1) * 64 + ln) * 8);
    bf16x8 bl1 = *(bf16x8*)(Bs + 4096 + ((size_t)(c0 + 1) * 64 + ln) * 8);
#pragma unroll
    for (int rg = 0; rg < 4; ++rg) {
      bf16x8 ah = *(bf16x8*)(As + ((size_t)rg * 64 + ln) * 8);
      acc[rg][0] = __builtin_amdgcn_mfma_f32_16x16x32_bf16(ah, bh0, acc[rg][0], 0, 0, 0);
      acc[rg][0] = __builtin_amdgcn_mfma_f32_16x16x32_bf16(ah, bl0, acc[rg][0], 0, 0, 0);
      acc[rg][1] = __builtin_amdgcn_mfma_f32_16x16x32_bf16(ah, bh1, acc[rg][1], 0, 0, 0);
      acc[rg][1] = __builtin_amdgcn_mfma_f32_16x16x32_bf16(ah, bl1, acc[rg][1], 0, 0, 0);
      if (doLo) {
        bf16x8 al = *(bf16x8*)(As + 2048 + ((size_t)rg * 64 + ln) * 8);
        acc[rg][0] = __builtin_amdgcn_mfma_f32_16x16x32_bf16(al, bh0, acc[rg][0], 0, 0, 0);
        acc[rg][1] = __builtin_amdgcn_mfma_f32_16x16x32_bf16(al, bh1, acc[rg][1], 0, 0, 0);
      }
    }
  }

  // epilogue: bias + relu. C layout: col=lane&15, row=(lane>>4)*4+reg (m89).
  int lcol = ln & 15;
  int rsub = (ln >> 4) * 4;
#pragma unroll
  for (int c = 0; c < 2; ++c) {
    float b = bias[(wv * 2 + c) * 16 + lcol];
#pragma unroll
    for (int rg = 0; rg < 4; ++rg)
#pragma unroll
      for (int r = 0; r < 4; ++r) acc[rg][c][r] = fmaxf(acc[rg][c][r] + b, 0.f);
  }

  if (mode == 0) {
#pragma unroll
    for (int rg = 0; rg < 4; ++rg)
#pragma unroll
      for (int r = 0; r < 4; ++r) {
        int row = rowBase + rg * 16 + rsub + r;
        if (row < N) {
          OUTbf[(size_t)row * 128 + (wv * 2 + 0) * 16 + lcol] = f2bf(acc[rg][0][r]);
          OUTbf[(size_t)row * 128 + (wv * 2 + 1) * 16 + lcol] = f2bf(acc[rg][1][r]);
        }
      }
  } else {
    if (tid < 128) ps[tid] = 0.f;
    __syncthreads();
    int lastRow = min(rowBase + 63, N - 1);
    int g0 = batch[rowBase], g1 = batch[lastRow];
    if (g0 == g1) {
#pragma unroll
      for (int c = 0; c < 2; ++c) {
        float s = 0.f;
#pragma unroll
        for (int rg = 0; rg < 4; ++rg)
#pragma unroll
          for (int r = 0; r < 4; ++r) {
            int row = rowBase + rg * 16 + rsub + r;
            if (row < N) s += acc[rg][c][r];
          }
        atomicAdd(&ps[(wv * 2 + c) * 16 + lcol], s);
      }
      __syncthreads();
      if (tid < 128) atomicAdd(&gsum[g0 * 128 + tid], ps[tid]);
    } else {
#pragma unroll
      for (int rg = 0; rg < 4; ++rg)
#pragma unroll
        for (int r = 0; r < 4; ++r) {
          int row = rowBase + rg * 16 + rsub + r;
          if (row < N) {
            int g = batch[row];
            atomicAdd(&gsum[g * 128 + (wv * 2 + 0) * 16 + lcol], acc[rg][0][r]);
            atomicAdd(&gsum[g * 128 + (wv * 2 + 1) * 16 + lcol], acc[rg][1][r]);
          }
        }
    }
  }
}

// ---- fused classifier: out[g] = (relu(gemb@Wc1.T+bc1)) @ Wc2.T + bc2 ------

__global__ __launch_bounds__(128) void k_cls(const float* __restrict__ gsum, const int* __restrict__ gcnt,
                                             const float* __restrict__ Wc1, const float* __restrict__ bc1,
                                             const float* __restrict__ Wc2, const float* __restrict__ bc2,
                                             float* __restrict__ out) {
  __shared__ float red[128];
  int g = blockIdx.x;
  int h = threadIdx.x;
  float inv = 1.0f / (float)max(gcnt[g], 1);
  float s = 0.f;
  for (int f = 0; f < 128; ++f) s += gsum[g * 128 + f] * Wc1[h * 128 + f];
  red[h] = fmaxf(s * inv + bc1[h], 0.f) * Wc2[h];
  __syncthreads();
  for (int d = 64; d > 0; d >>= 1) {
    if (h < d) red[h] += red[h + d];
    __syncthreads();
  }
  if (h == 0) out[g] = red[0] + bc2[0];
}

// ---------------------------------------------------------------------------

extern "C" void kernel_launch(void* const* d_in, const int* in_sizes, int n_in,
                              void* d_out, int out_size, void* d_ws, size_t ws_size,
                              hipStream_t stream) {
  const float* x   = (const float*)d_in[0];
  const int*   ei  = (const int*)d_in[1];
  const int*   bat = (const int*)d_in[2];
  const float* W1l = (const float*)d_in[3];
  const float* b1l = (const float*)d_in[4];
  const float* W1r = (const float*)d_in[5];
  const float* W2l = (const float*)d_in[6];
  const float* b2l = (const float*)d_in[7];
  const float* W2r = (const float*)d_in[8];
  const float* Wc1 = (const float*)d_in[9];
  const float* bc1 = (const float*)d_in[10];
  const float* Wc2 = (const float*)d_in[11];
  const float* bc2 = (const float*)d_in[12];
  float* out = (float*)d_out;

  int N = in_sizes[0] / 128;
  int E = in_sizes[1] / 2;
  int nEblk = (E + HBLK - 1) / HBLK;       // 147
  int nBuk = (N + 255) >> 8;               // 196
  int total = N * 128;
  int nTobf = (total / 4 + 255) / 256;     // 6250

  char* ws = (char*)d_ws;
  size_t o = 0;
  auto alloc = [&](size_t bytes) {
    char* p = ws + o;
    o += (bytes + 255) & ~(size_t)255;
    return p;
  };
  int*      off    = (int*)alloc((size_t)(N + 1) * 4);
  int*      col    = (int*)alloc((size_t)E * 4);
  unsigned* ebuk   = (unsigned*)alloc((size_t)E * 4);
  int*      bhist  = (int*)alloc((size_t)nEblk * 256 * 4);
  int*      bukbase= (int*)alloc(257 * 4);
  unsigned short* Tbf  = (unsigned short*)alloc((size_t)N * 128 * 2);
  unsigned short* xbf  = (unsigned short*)alloc((size_t)N * 128 * 2);
  unsigned short* h1bf = (unsigned short*)alloc((size_t)N * 128 * 2);
  unsigned short* Bpre1 = (unsigned short*)alloc(65536 * 2);
  unsigned short* Bpre2 = (unsigned short*)alloc(65536 * 2);
  float*    gsum   = (float*)alloc(64 * 128 * 4 + 64 * 4);
  int*      gcnt   = (int*)(gsum + 64 * 128);

  // fused prep (tobf | wprep1 | wprep2 | hist | gcnt+gsum0)
  k_prep<<<nTobf + 32 + nEblk + 1, 256, 0, stream>>>(
      x, xbf, total, W1l, W1r, Bpre1, W2l, W2r, Bpre2,
      bat, gcnt, gsum, N, ei, bhist, E, nTobf, nEblk);

  // CSR build
  k_bscan_a<<<1, 256, 0, stream>>>(bhist, bukbase, nEblk);
  k_bscan_b<<<256, 256, 0, stream>>>(bhist, bukbase, nEblk);
  k_scat<<<nEblk, 256, 0, stream>>>(ei, bhist, ebuk, E);
  k_bucket<<<nBuk, 256, 0, stream>>>(ebuk, bukbase, off, col, N, E);

  int nLinBlk = (N + 63) / 64;
  // layer 1: agg(xbf) -> Tbf; lin(Tbf, x fp32) -> h1bf
  k_agg_bf<<<(N + 3) / 4, 256, 0, stream>>>(xbf, off, col, Tbf, N);
  k_lin_mfma<<<nLinBlk, 256, 0, stream>>>(Tbf, x, nullptr, Bpre1, b1l, h1bf, bat, gsum, N, 0);
  // layer 2: agg(h1bf) -> Tbf; lin(Tbf, h1bf) -> pooled gsum
  k_agg_bf<<<(N + 3) / 4, 256, 0, stream>>>(h1bf, off, col, Tbf, N);
  k_lin_mfma<<<nLinBlk, 256, 0, stream>>>(Tbf, nullptr, h1bf, Bpre2, b2l, nullptr, bat, gsum, N, 1);

  // classifier
  k_cls<<<64, 128, 0, stream>>>(gsum, gcnt, Wc1, bc1, Wc2, bc2, out);
}